// Round 3
// baseline (18853.627 us; speedup 1.0000x reference)
//
#include <hip/hip_runtime.h>

typedef _Float16 f16x8 __attribute__((ext_vector_type(8)));
typedef _Float16 f16x4 __attribute__((ext_vector_type(4)));
typedef float    f32x4 __attribute__((ext_vector_type(4)));

#define HID 1024
#define TT  512
#define BB  64
#define MROWS (TT*BB)   // 32768
#define G3  (3*HID)     // 3072
#define NWG 64          // scan workgroups (1 per CU, all co-resident)
#define BH  (BB*HID)    // 65536

__device__ __forceinline__ f32x4 mfma16(f16x8 a, f16x8 b, f32x4 c) {
  return __builtin_amdgcn_mfma_f32_16x16x32_f16(a, b, c, 0, 0, 0);
}

// async global->LDS, 16B per lane. lds ptr must be the wave-uniform base.
__device__ __forceinline__ void g2l16(const _Float16* g, _Float16* l) {
  __builtin_amdgcn_global_load_lds(
      (const __attribute__((address_space(1))) unsigned int*)g,
      (__attribute__((address_space(3))) unsigned int*)l, 16, 0, 0);
}

__device__ __forceinline__ float sigm(float x) { return 1.f / (1.f + __expf(-x)); }
__device__ __forceinline__ float tanh_f(float x) {
  x = fminf(fmaxf(x, -20.f), 20.f);
  float e = __expf(2.f * x);
  return (e - 1.f) / (e + 1.f);
}

// ---------------- prep: fp32 -> fp16 casts (+ K-pad 118->128, x transpose to [t][b]) -----
__global__ __launch_bounds__(256) void prep_kernel(
    const float* __restrict__ x, const float* __restrict__ wih0,
    const float* __restrict__ wih12, const float* __restrict__ whh,
    _Float16* __restrict__ x16, _Float16* __restrict__ wi0_16,
    _Float16* __restrict__ wi12_16, _Float16* __restrict__ whh16,
    unsigned* __restrict__ flags)
{
  if (blockIdx.x == 0 && threadIdx.x < NWG) flags[threadIdx.x] = 0u;  // ws is 0xAA-poisoned

  const int R0 = MROWS * 128;
  const int R1 = G3 * 128;
  const int R2 = 2 * G3 * HID;
  const int R3 = 3 * G3 * HID;
  const int total = R0 + R1 + R2 + R3;
  for (int idx = blockIdx.x * 256 + threadIdx.x; idx < total; idx += gridDim.x * 256) {
    if (idx < R0) {                       // x16[t*64+b][128]
      int row = idx >> 7, k = idx & 127;
      int t = row >> 6, b = row & 63;
      x16[idx] = (k < 118) ? (_Float16)x[((size_t)b * TT + t) * 118 + k] : (_Float16)0.f;
    } else if (idx < R0 + R1) {           // W_ih0 padded [3072][128]
      int i = idx - R0;
      int row = i >> 7, k = i & 127;
      wi0_16[i] = (k < 118) ? (_Float16)wih0[(size_t)row * 118 + k] : (_Float16)0.f;
    } else if (idx < R0 + R1 + R2) {      // W_ih12 [2][3072][1024]
      int i = idx - (R0 + R1);
      wi12_16[i] = (_Float16)wih12[i];
    } else {                              // W_hh [3][3072][1024]
      int i = idx - (R0 + R1 + R2);
      whh16[i] = (_Float16)whh[i];
    }
  }
}

// ---------------- input-projection GEMM: xg[t_loc][col][b] = A[t_loc*64+b][K] @ W[col][K]^T
// m97 structure: 128x128 tile, BK=32, 4 waves (2x2), 4x4 16x16x32 frags per wave.
// A is pre-offset to the chunk; xg is chunk-local [C][3072][64].
__global__ __launch_bounds__(256) void gemm_xg_kernel(
    const _Float16* __restrict__ A, const _Float16* __restrict__ W,
    const float* __restrict__ bias, _Float16* __restrict__ xg, int K)
{
  __shared__ __align__(16) _Float16 As[128 * 32];
  __shared__ __align__(16) _Float16 Bs[128 * 32];
  const int tid = threadIdx.x, l = tid & 63, wv = tid >> 6;
  const int wm = wv >> 1, wn = wv & 1;
  const size_t m0 = (size_t)blockIdx.y * 128, n0 = (size_t)blockIdx.x * 128;

  f32x4 acc[4][4];
#pragma unroll
  for (int i = 0; i < 4; ++i)
#pragma unroll
    for (int j = 0; j < 4; ++j) acc[i][j] = f32x4{0.f, 0.f, 0.f, 0.f};

  for (int kt = 0; kt < K; kt += 32) {
#pragma unroll
    for (int rr = 0; rr < 2; ++rr) {
      const int ca = rr * 256 + tid;          // 16B chunk id, = wave_base + lane
      const int row = ca >> 2, cir = ca & 3;  // 4 chunks (64B) per tile row
      const _Float16* ga = A + (m0 + row) * (size_t)K + kt + cir * 8;
      const _Float16* gb = W + (n0 + row) * (size_t)K + kt + cir * 8;
      _Float16* la = As + (rr * 256 + wv * 64) * 8;  // wave-uniform LDS base
      _Float16* lb = Bs + (rr * 256 + wv * 64) * 8;
      g2l16(ga, la);
      g2l16(gb, lb);
    }
    __syncthreads();
    f16x8 af[4], bf[4];
#pragma unroll
    for (int mt = 0; mt < 4; ++mt)
      af[mt] = *reinterpret_cast<const f16x8*>(As + (wm * 64 + mt * 16 + (l & 15)) * 32 + ((l >> 4) << 3));
#pragma unroll
    for (int nt = 0; nt < 4; ++nt)
      bf[nt] = *reinterpret_cast<const f16x8*>(Bs + (wn * 64 + nt * 16 + (l & 15)) * 32 + ((l >> 4) << 3));
#pragma unroll
    for (int mt = 0; mt < 4; ++mt)
#pragma unroll
      for (int nt = 0; nt < 4; ++nt)
        acc[mt][nt] = mfma16(af[mt], bf[nt], acc[mt][nt]);
    __syncthreads();
  }

  // epilogue: rows of a 128-tile are (t0+wm, b = mt*16+(l>>4)*4+r); pack 4 consecutive b.
  const int t0 = blockIdx.y * 2 + wm;
#pragma unroll
  for (int nt = 0; nt < 4; ++nt) {
    const int col = (int)n0 + wn * 64 + nt * 16 + (l & 15);
    const float bv = bias[col];
#pragma unroll
    for (int mt = 0; mt < 4; ++mt) {
      const int bq = mt * 16 + ((l >> 4) << 2);
      f16x4 o;
#pragma unroll
      for (int r = 0; r < 4; ++r) o[r] = (_Float16)(acc[mt][nt][r] + bv);
      *reinterpret_cast<f16x4*>(xg + ((size_t)t0 * G3 + col) * 64 + bq) = o;
    }
  }
}

// ---------------- GRU scan over one chunk (manual persistent barrier) ----------------
// grid = 64 wgs x 256 thr, 1 wg/CU (96KB LDS). wg owns output cols j0..j0+15 (3 gate
// stripes of W_hh weight-stationary, XOR-swizzled LDS). wave w owns batch rows 16w..16w+15.
// Recurrent state across chunk dispatches: h32L fp32 master + h16L fp16 double-buffer.
// Barrier: per-wg generation flags (monotone across dispatches), agent-scope rel/acq.
__global__ __launch_bounds__(256, 1) void gru_scan_kernel(
    const _Float16* __restrict__ xg,   // chunk-local [steps][3072][64]
    const _Float16* __restrict__ Wl,   // W_hh16 layer [3072][1024]
    const float* __restrict__ bhh,     // [3072]
    _Float16* __restrict__ y16,        // chunk-local [steps*64][1024] or nullptr
    float* h32L,                       // [64][1024] fp32 master state (this layer)
    _Float16* h16L,                    // [2][64][1024] fp16 state (this layer)
    unsigned* flags,                   // [NWG] monotone generation flags
    int steps, int t0g, int zero_h, unsigned g0)
{
  __shared__ __align__(16) _Float16 WL[48 * 1024];  // 96 KB
  const int tid = threadIdx.x, l = tid & 63, w = tid >> 6;
  const int j0 = blockIdx.x * 16;
  char* wl_b = reinterpret_cast<char*>(WL);

  // load W slice (rows: gi*16+jr <- global row gi*1024+j0+jr), XOR-swizzled (G4 fix)
  for (int c = tid; c < 48 * 128; c += 256) {
    const int lr = c >> 7, kc = c & 127;
    const int gi = lr >> 4, jr = lr & 15;
    const _Float16* src = Wl + (size_t)(gi * HID + j0 + jr) * HID + kc * 8;
    unsigned int byte = (unsigned)(lr * 2048 + kc * 16) ^ (unsigned)((lr & 7) << 4);
    *reinterpret_cast<uint4*>(wl_b + byte) = *reinterpret_cast<const uint4*>(src);
  }
  if (zero_h) {  // zero both h16 parity buffers (grid-wide: 16384 float4 / 16384 thr)
    const int i = blockIdx.x * 256 + tid;
    reinterpret_cast<float4*>(h16L)[i] = make_float4(0.f, 0.f, 0.f, 0.f);
  }

  const int jj = j0 + (l & 15);            // this lane's output column
  const int b0 = 16 * w + ((l >> 4) << 2); // first of 4 batch rows (C/D row map)
  const float bhr = bhh[jj], bhz = bhh[HID + jj], bhn = bhh[2 * HID + jj];
  float hold[4];
#pragma unroll
  for (int r = 0; r < 4; ++r)
    hold[r] = zero_h ? 0.f : h32L[(size_t)(b0 + r) * HID + jj];
  const int arow = (16 * w + (l & 15)) * HID;  // A-frag row (A map: row = l&15)
  const int kq = (l >> 4) << 3;                // A/B frag k-offset (elements)
  const int kqb = kq * 2;

  unsigned gen = g0;
  // ---- initial barrier: h16 zeroing visible grid-wide ----
  __syncthreads();
  if (tid == 0) {
    __threadfence();
    __hip_atomic_store(&flags[blockIdx.x], gen, __ATOMIC_RELEASE, __HIP_MEMORY_SCOPE_AGENT);
  }
  if (tid < NWG) {
    while (__hip_atomic_load(&flags[tid], __ATOMIC_ACQUIRE, __HIP_MEMORY_SCOPE_AGENT) < gen)
      __builtin_amdgcn_s_sleep(2);
  }
  __syncthreads();
  ++gen;

  // prefetch xg for t=0
  f16x4 xr4, xz4, xn4;
  {
    const size_t xb = ((size_t)0 * G3 + jj) * 64 + b0;
    xr4 = *reinterpret_cast<const f16x4*>(xg + xb);
    xz4 = *reinterpret_cast<const f16x4*>(xg + xb + (size_t)HID * 64);
    xn4 = *reinterpret_cast<const f16x4*>(xg + xb + (size_t)2 * HID * 64);
  }

  for (int t = 0; t < steps; ++t) {
    const int p = (t0g + t) & 1;
    const _Float16* hr16 = h16L + (size_t)p * BH;
    _Float16* hw16 = h16L + (size_t)(p ^ 1) * BH;

    f32x4 acc[3];
#pragma unroll
    for (int gi = 0; gi < 3; ++gi) acc[gi] = f32x4{0.f, 0.f, 0.f, 0.f};

#pragma unroll
    for (int kb = 0; kb < 4; ++kb) {
      f16x8 afr[8];
#pragma unroll
      for (int kk = 0; kk < 8; ++kk)
        afr[kk] = *reinterpret_cast<const f16x8*>(hr16 + arow + kb * 256 + kk * 32 + kq);
#pragma unroll
      for (int kk = 0; kk < 8; ++kk) {
        const int kbyte = (kb * 256 + kk * 32) * 2 + kqb;
#pragma unroll
        for (int gi = 0; gi < 3; ++gi) {
          const int lr = gi * 16 + (l & 15);
          const unsigned int off = (unsigned)(lr * 2048 + kbyte) ^ (unsigned)((lr & 7) << 4);
          f16x8 bfr = *reinterpret_cast<const f16x8*>(wl_b + off);
          acc[gi] = mfma16(afr[kk], bfr, acc[gi]);
        }
      }
    }

    _Float16 hout[4];
#pragma unroll
    for (int r = 0; r < 4; ++r) {
      const float rg = sigm((float)xr4[r] + acc[0][r] + bhr);
      const float zg = sigm((float)xz4[r] + acc[1][r] + bhz);
      const float ng = tanh_f((float)xn4[r] + rg * (acc[2][r] + bhn));
      const float hv = (1.f - zg) * ng + zg * hold[r];
      hold[r] = hv;
      hout[r] = (_Float16)hv;
    }
#pragma unroll
    for (int r = 0; r < 4; ++r) hw16[(size_t)(b0 + r) * HID + jj] = hout[r];
    if (y16) {
#pragma unroll
      for (int r = 0; r < 4; ++r) y16[((size_t)t * BB + b0 + r) * HID + jj] = hout[r];
    }

    // ---- end-of-step barrier: arrive, prefetch next xg under the spin, poll ----
    __syncthreads();              // all wg threads' h/y stores issued
    if (tid == 0) {
      __threadfence();            // agent fence: cross-XCD L2 writeback+inv
      __hip_atomic_store(&flags[blockIdx.x], gen, __ATOMIC_RELEASE, __HIP_MEMORY_SCOPE_AGENT);
    }
    if (t + 1 < steps) {          // next-step xg loads complete while we spin
      const size_t xb = ((size_t)(t + 1) * G3 + jj) * 64 + b0;
      xr4 = *reinterpret_cast<const f16x4*>(xg + xb);
      xz4 = *reinterpret_cast<const f16x4*>(xg + xb + (size_t)HID * 64);
      xn4 = *reinterpret_cast<const f16x4*>(xg + xb + (size_t)2 * HID * 64);
    }
    if (tid < NWG) {
      while (__hip_atomic_load(&flags[tid], __ATOMIC_ACQUIRE, __HIP_MEMORY_SCOPE_AGENT) < gen)
        __builtin_amdgcn_s_sleep(2);
    }
    __syncthreads();
    ++gen;
  }

  // persist fp32 master state for the next chunk dispatch
#pragma unroll
  for (int r = 0; r < 4; ++r) h32L[(size_t)(b0 + r) * HID + jj] = hold[r];
}

// ---------------- final linear: out[b] = dot(h32[b,:], Wlin) + blin ----------------
__global__ __launch_bounds__(256) void linear_kernel(
    const float* __restrict__ h32, const float* __restrict__ wlin,
    const float* __restrict__ blin, float* __restrict__ out)
{
  __shared__ float red[4];
  const int b = blockIdx.x, tid = threadIdx.x;
  float s = 0.f;
  for (int j = tid; j < HID; j += 256) s += h32[(size_t)b * HID + j] * wlin[j];
  for (int o = 32; o > 0; o >>= 1) s += __shfl_down(s, o);
  if ((tid & 63) == 0) red[tid >> 6] = s;
  __syncthreads();
  if (tid == 0) out[b] = red[0] + red[1] + red[2] + red[3] + blin[0];
}

extern "C" void kernel_launch(void* const* d_in, const int* in_sizes, int n_in,
                              void* d_out, int out_size, void* d_ws, size_t ws_size,
                              hipStream_t stream) {
  const float* x     = (const float*)d_in[0];
  const float* wih0  = (const float*)d_in[1];
  const float* wih12 = (const float*)d_in[2];
  const float* whh   = (const float*)d_in[3];
  const float* bih   = (const float*)d_in[4];
  const float* bhh   = (const float*)d_in[5];
  const float* wlin  = (const float*)d_in[6];
  const float* blin  = (const float*)d_in[7];
  float* out = (float*)d_out;

  // ---- adaptive chunking: fit workspace to ws_size (deterministic per call) ----
  // fixed: X16 8.39MB + WI0 0.79 + WI12 12.58 + WHH 18.87 + H16 0.79 + H32 0.79 + flags
  const size_t fixedB = 8388608ull + 786432 + 12582912 + 18874368 + 786432 + 786432 + 1024;
  int C = 8;
  {
    const int cands[7] = {512, 256, 128, 64, 32, 16, 8};
    for (int i = 0; i < 7; ++i) {
      if (fixedB + (size_t)cands[i] * 524288ull <= ws_size) { C = cands[i]; break; }
    }
  }
  const int nch = TT / C;

  char* ws = (char*)d_ws;
  size_t o = 0;
  _Float16* XG  = (_Float16*)(ws + o); o += (size_t)C * G3 * BB * 2;    // C*384KB
  _Float16* Ych = (_Float16*)(ws + o); o += (size_t)C * BB * HID * 2;   // C*128KB
  _Float16* X16 = (_Float16*)(ws + o); o += (size_t)MROWS * 128 * 2;    // 8.39MB
  _Float16* WI0 = (_Float16*)(ws + o); o += (size_t)G3 * 128 * 2;
  _Float16* WI12= (_Float16*)(ws + o); o += (size_t)2 * G3 * HID * 2;
  _Float16* WHH = (_Float16*)(ws + o); o += (size_t)3 * G3 * HID * 2;
  _Float16* H16 = (_Float16*)(ws + o); o += (size_t)3 * 2 * BH * 2;     // per-layer dbuf
  float*    H32 = (float*)(ws + o);    o += (size_t)3 * BH * 4;         // per-layer master
  unsigned* FLG = (unsigned*)(ws + o); o += 1024;

  prep_kernel<<<dim3(2048), dim3(256), 0, stream>>>(x, wih0, wih12, whh,
                                                    X16, WI0, WI12, WHH, FLG);

  unsigned g0 = 1;
  for (int c = 0; c < nch; ++c) {
    for (int layer = 0; layer < 3; ++layer) {
      const _Float16* A  = (layer == 0) ? X16 + (size_t)c * C * 64 * 128 : Ych;
      const int K        = (layer == 0) ? 128 : HID;
      const _Float16* WI = (layer == 0) ? WI0 : WI12 + (size_t)(layer - 1) * G3 * HID;
      gemm_xg_kernel<<<dim3(24, C / 2), dim3(256), 0, stream>>>(
          A, WI, bih + layer * G3, XG, K);

      gru_scan_kernel<<<dim3(NWG), dim3(256), 0, stream>>>(
          XG, WHH + (size_t)layer * G3 * HID, bhh + layer * G3,
          (layer < 2) ? Ych : (_Float16*)nullptr,
          H32 + (size_t)layer * BH, H16 + (size_t)layer * 2 * BH,
          FLG, C, c * C, (c == 0) ? 1 : 0, g0);
      g0 += (unsigned)(C + 1);
    }
  }

  linear_kernel<<<dim3(64), dim3(256), 0, stream>>>(H32 + 2 * (size_t)BH, wlin, blin, out);
}

// Round 4
// 11629.906 us; speedup vs baseline: 1.6211x; 1.6211x over previous
//
#include <hip/hip_runtime.h>

typedef _Float16 f16x8 __attribute__((ext_vector_type(8)));
typedef _Float16 f16x4 __attribute__((ext_vector_type(4)));
typedef float    f32x4 __attribute__((ext_vector_type(4)));

#define HID 1024
#define TT  512
#define BB  64
#define MROWS (TT*BB)   // 32768
#define G3  (3*HID)     // 3072
#define NWG 64          // scan workgroups (1 per CU, all co-resident)
#define BH  (BB*HID)    // 65536

__device__ __forceinline__ f32x4 mfma16(f16x8 a, f16x8 b, f32x4 c) {
  return __builtin_amdgcn_mfma_f32_16x16x32_f16(a, b, c, 0, 0, 0);
}

// async global->LDS, 16B per lane. lds ptr must be the wave-uniform base.
__device__ __forceinline__ void g2l16(const _Float16* g, _Float16* l) {
  __builtin_amdgcn_global_load_lds(
      (const __attribute__((address_space(1))) unsigned int*)g,
      (__attribute__((address_space(3))) unsigned int*)l, 16, 0, 0);
}

__device__ __forceinline__ float sigm(float x) { return 1.f / (1.f + __expf(-x)); }
__device__ __forceinline__ float tanh_f(float x) {
  x = fminf(fmaxf(x, -20.f), 20.f);
  float e = __expf(2.f * x);
  return (e - 1.f) / (e + 1.f);
}

// ---- device-scope (IC-coherent) accessors: sc1 = device scope, bypass L1/L2 ----
#define H_LOAD16(dst, src) \
  asm volatile("global_load_dwordx4 %0, %1, off sc1" : "=v"(dst) : "v"(src))
#define H_STORE2(ptr, val16) \
  asm volatile("global_store_short %0, %1, off sc1" \
               :: "v"(ptr), "v"((unsigned)__builtin_bit_cast(unsigned short, (val16))) : "memory")
#define H_STORE16(ptr, v4) \
  asm volatile("global_store_dwordx4 %0, %1, off sc1" :: "v"(ptr), "v"(v4) : "memory")
#define WAIT_VM0 \
  do { asm volatile("s_waitcnt vmcnt(0)" ::: "memory"); } while (0)

// ---------------- prep: fp32 -> fp16 casts (+ K-pad 118->128, x transpose to [t][b]) -----
__global__ __launch_bounds__(256) void prep_kernel(
    const float* __restrict__ x, const float* __restrict__ wih0,
    const float* __restrict__ wih12, const float* __restrict__ whh,
    _Float16* __restrict__ x16, _Float16* __restrict__ wi0_16,
    _Float16* __restrict__ wi12_16, _Float16* __restrict__ whh16,
    unsigned* __restrict__ flags)
{
  if (blockIdx.x == 0 && threadIdx.x < NWG) flags[threadIdx.x] = 0u;  // ws is 0xAA-poisoned

  const int R0 = MROWS * 128;
  const int R1 = G3 * 128;
  const int R2 = 2 * G3 * HID;
  const int R3 = 3 * G3 * HID;
  const int total = R0 + R1 + R2 + R3;
  for (int idx = blockIdx.x * 256 + threadIdx.x; idx < total; idx += gridDim.x * 256) {
    if (idx < R0) {                       // x16[t*64+b][128]
      int row = idx >> 7, k = idx & 127;
      int t = row >> 6, b = row & 63;
      x16[idx] = (k < 118) ? (_Float16)x[((size_t)b * TT + t) * 118 + k] : (_Float16)0.f;
    } else if (idx < R0 + R1) {           // W_ih0 padded [3072][128]
      int i = idx - R0;
      int row = i >> 7, k = i & 127;
      wi0_16[i] = (k < 118) ? (_Float16)wih0[(size_t)row * 118 + k] : (_Float16)0.f;
    } else if (idx < R0 + R1 + R2) {      // W_ih12 [2][3072][1024]
      int i = idx - (R0 + R1);
      wi12_16[i] = (_Float16)wih12[i];
    } else {                              // W_hh [3][3072][1024]
      int i = idx - (R0 + R1 + R2);
      whh16[i] = (_Float16)whh[i];
    }
  }
}

// ---------------- input-projection GEMM: xg[t_loc][col][b] = A[t_loc*64+b][K] @ W[col][K]^T
// m97 structure: 128x128 tile, BK=32, 4 waves (2x2), 4x4 16x16x32 frags per wave.
__global__ __launch_bounds__(256) void gemm_xg_kernel(
    const _Float16* __restrict__ A, const _Float16* __restrict__ W,
    const float* __restrict__ bias, _Float16* __restrict__ xg, int K)
{
  __shared__ __align__(16) _Float16 As[128 * 32];
  __shared__ __align__(16) _Float16 Bs[128 * 32];
  const int tid = threadIdx.x, l = tid & 63, wv = tid >> 6;
  const int wm = wv >> 1, wn = wv & 1;
  const size_t m0 = (size_t)blockIdx.y * 128, n0 = (size_t)blockIdx.x * 128;

  f32x4 acc[4][4];
#pragma unroll
  for (int i = 0; i < 4; ++i)
#pragma unroll
    for (int j = 0; j < 4; ++j) acc[i][j] = f32x4{0.f, 0.f, 0.f, 0.f};

  for (int kt = 0; kt < K; kt += 32) {
#pragma unroll
    for (int rr = 0; rr < 2; ++rr) {
      const int ca = rr * 256 + tid;          // 16B chunk id, = wave_base + lane
      const int row = ca >> 2, cir = ca & 3;  // 4 chunks (64B) per tile row
      const _Float16* ga = A + (m0 + row) * (size_t)K + kt + cir * 8;
      const _Float16* gb = W + (n0 + row) * (size_t)K + kt + cir * 8;
      _Float16* la = As + (rr * 256 + wv * 64) * 8;  // wave-uniform LDS base
      _Float16* lb = Bs + (rr * 256 + wv * 64) * 8;
      g2l16(ga, la);
      g2l16(gb, lb);
    }
    __syncthreads();
    f16x8 af[4], bf[4];
#pragma unroll
    for (int mt = 0; mt < 4; ++mt)
      af[mt] = *reinterpret_cast<const f16x8*>(As + (wm * 64 + mt * 16 + (l & 15)) * 32 + ((l >> 4) << 3));
#pragma unroll
    for (int nt = 0; nt < 4; ++nt)
      bf[nt] = *reinterpret_cast<const f16x8*>(Bs + (wn * 64 + nt * 16 + (l & 15)) * 32 + ((l >> 4) << 3));
#pragma unroll
    for (int mt = 0; mt < 4; ++mt)
#pragma unroll
      for (int nt = 0; nt < 4; ++nt)
        acc[mt][nt] = mfma16(af[mt], bf[nt], acc[mt][nt]);
    __syncthreads();
  }

  // epilogue: rows of a 128-tile are (t0+wm, b = mt*16+(l>>4)*4+r); pack 4 consecutive b.
  const int t0 = blockIdx.y * 2 + wm;
#pragma unroll
  for (int nt = 0; nt < 4; ++nt) {
    const int col = (int)n0 + wn * 64 + nt * 16 + (l & 15);
    const float bv = bias[col];
#pragma unroll
    for (int mt = 0; mt < 4; ++mt) {
      const int bq = mt * 16 + ((l >> 4) << 2);
      f16x4 o;
#pragma unroll
      for (int r = 0; r < 4; ++r) o[r] = (_Float16)(acc[mt][nt][r] + bv);
      *reinterpret_cast<f16x4*>(xg + ((size_t)t0 * G3 + col) * 64 + bq) = o;
    }
  }
}

// one K-block of the hg MFMA: counted vmcnt so IC latency overlaps earlier blocks' MFMA.
// sched_barrier after the waitcnt per rule #18 (asm waitcnt doesn't order reg-only MFMA).
#define MFMA_KB(kb, WCNT)                                                      \
  {                                                                            \
    asm volatile("s_waitcnt vmcnt(" WCNT ")" ::: "memory");                    \
    __builtin_amdgcn_sched_barrier(0);                                         \
    _Pragma("unroll")                                                          \
    for (int kk = 0; kk < 8; ++kk) {                                           \
      const int kbyte = ((kb) * 256 + kk * 32) * 2 + kqb;                      \
      _Pragma("unroll")                                                        \
      for (int gi = 0; gi < 3; ++gi) {                                         \
        const int lr = gi * 16 + (l & 15);                                     \
        const unsigned off = (unsigned)(lr * 2048 + kbyte) ^ (unsigned)((lr & 7) << 4); \
        f16x8 bfr = *reinterpret_cast<const f16x8*>(wl_b + off);               \
        acc[gi] = mfma16(afr[kb][kk], bfr, acc[gi]);                           \
      }                                                                        \
    }                                                                          \
  }

// ---------------- GRU scan over one chunk (manual persistent barrier) ----------------
// grid = 64 wgs x 256 thr, 1 wg/CU (96KB LDS). wg owns output cols j0..j0+15 (3 gate
// stripes of W_hh weight-stationary, XOR-swizzled LDS). wave w owns batch rows 16w..16w+15.
// Cross-WG h exchange via sc1 (device-scope, IC-coherent) loads/stores: NO cache
// maintenance (no wbl2/inv) anywhere -> L2 keeps xg/W warm, barrier = flag RTT only.
__global__ __launch_bounds__(256, 1) void gru_scan_kernel(
    const _Float16* __restrict__ xg,   // chunk-local [steps][3072][64]
    const _Float16* __restrict__ Wl,   // W_hh16 layer [3072][1024]
    const float* __restrict__ bhh,     // [3072]
    _Float16* __restrict__ y16,        // chunk-local [steps*64][1024] or nullptr
    float* h32L,                       // [64][1024] fp32 master state (this layer)
    _Float16* h16L,                    // [2][64][1024] fp16 state (this layer, sc1-only)
    unsigned* flags,                   // [NWG] monotone generation flags
    int steps, int t0g, int zero_h, unsigned g0)
{
  __shared__ __align__(16) _Float16 WL[48 * 1024];  // 96 KB
  const int tid = threadIdx.x, l = tid & 63, w = tid >> 6;
  const int j0 = blockIdx.x * 16;
  char* wl_b = reinterpret_cast<char*>(WL);

  // load W slice (rows: gi*16+jr <- global row gi*1024+j0+jr), XOR-swizzled (G4 fix)
  for (int c = tid; c < 48 * 128; c += 256) {
    const int lr = c >> 7, kc = c & 127;
    const int gi = lr >> 4, jr = lr & 15;
    const _Float16* src = Wl + (size_t)(gi * HID + j0 + jr) * HID + kc * 8;
    unsigned int byte = (unsigned)(lr * 2048 + kc * 16) ^ (unsigned)((lr & 7) << 4);
    *reinterpret_cast<uint4*>(wl_b + byte) = *reinterpret_cast<const uint4*>(src);
  }
  if (zero_h) {  // zero both h16 parity buffers with sc1 stores (readers bypass L2!)
    const int i = blockIdx.x * 256 + tid;
    f32x4 z = {0.f, 0.f, 0.f, 0.f};
    H_STORE16(reinterpret_cast<f32x4*>(h16L) + i, z);
  }

  const int jj = j0 + (l & 15);            // this lane's output column
  const int b0 = 16 * w + ((l >> 4) << 2); // first of 4 batch rows (C/D row map)
  const float bhr = bhh[jj], bhz = bhh[HID + jj], bhn = bhh[2 * HID + jj];
  float hold[4];
#pragma unroll
  for (int r = 0; r < 4; ++r)
    hold[r] = zero_h ? 0.f : h32L[(size_t)(b0 + r) * HID + jj];
  const int arow = (16 * w + (l & 15)) * HID;  // A-frag row (A map: row = l&15)
  const int kq = (l >> 4) << 3;                // A/B frag k-offset (elements)
  const int kqb = kq * 2;

  unsigned gen = g0;
  // ---- initial barrier: zeroing visible (sc1 acked at IC before flag) ----
  WAIT_VM0;
  __syncthreads();
  if (tid == 0)
    __hip_atomic_store(&flags[blockIdx.x], gen, __ATOMIC_RELAXED, __HIP_MEMORY_SCOPE_AGENT);
  if (tid < NWG) {
    while (__hip_atomic_load(&flags[tid], __ATOMIC_RELAXED, __HIP_MEMORY_SCOPE_AGENT) < gen)
      __builtin_amdgcn_s_sleep(2);
  }
  __syncthreads();
  ++gen;

  // prefetch xg for t=0 (normal cached loads)
  f16x4 xr4, xz4, xn4;
  {
    const size_t xb = ((size_t)0 * G3 + jj) * 64 + b0;
    xr4 = *reinterpret_cast<const f16x4*>(xg + xb);
    xz4 = *reinterpret_cast<const f16x4*>(xg + xb + (size_t)HID * 64);
    xn4 = *reinterpret_cast<const f16x4*>(xg + xb + (size_t)2 * HID * 64);
  }

  for (int t = 0; t < steps; ++t) {
    const int p = (t0g + t) & 1;
    const _Float16* hr16 = h16L + (size_t)p * BH;
    _Float16* hw16 = h16L + (size_t)(p ^ 1) * BH;

    f32x4 acc[3];
#pragma unroll
    for (int gi = 0; gi < 3; ++gi) acc[gi] = f32x4{0.f, 0.f, 0.f, 0.f};

    // issue all 32 h-loads (sc1: straight from IC), then counted waits per K-block
    f16x8 afr[4][8];
#pragma unroll
    for (int kb = 0; kb < 4; ++kb)
#pragma unroll
      for (int kk = 0; kk < 8; ++kk)
        H_LOAD16(afr[kb][kk], hr16 + arow + kq + kb * 256 + kk * 32);

    MFMA_KB(0, "24")
    MFMA_KB(1, "16")
    MFMA_KB(2, "8")
    MFMA_KB(3, "0")

    _Float16 hout[4];
#pragma unroll
    for (int r = 0; r < 4; ++r) {
      const float rg = sigm((float)xr4[r] + acc[0][r] + bhr);
      const float zg = sigm((float)xz4[r] + acc[1][r] + bhz);
      const float ng = tanh_f((float)xn4[r] + rg * (acc[2][r] + bhn));
      const float hv = (1.f - zg) * ng + zg * hold[r];
      hold[r] = hv;
      hout[r] = (_Float16)hv;
    }
#pragma unroll
    for (int r = 0; r < 4; ++r) H_STORE2(hw16 + (size_t)(b0 + r) * HID + jj, hout[r]);
    if (y16) {  // layer output: normal cached stores (consumed by next kernel)
#pragma unroll
      for (int r = 0; r < 4; ++r) y16[((size_t)t * BB + b0 + r) * HID + jj] = hout[r];
    }

    // ---- end-of-step barrier: drain own stores, arrive, prefetch, relaxed-poll ----
    WAIT_VM0;                     // own sc1 h-stores acked at IC (and y16 at L2)
    __syncthreads();              // all waves of this WG drained
    if (tid == 0)
      __hip_atomic_store(&flags[blockIdx.x], gen, __ATOMIC_RELAXED, __HIP_MEMORY_SCOPE_AGENT);
    if (t + 1 < steps) {          // next-step xg loads complete while we spin
      const size_t xb = ((size_t)(t + 1) * G3 + jj) * 64 + b0;
      xr4 = *reinterpret_cast<const f16x4*>(xg + xb);
      xz4 = *reinterpret_cast<const f16x4*>(xg + xb + (size_t)HID * 64);
      xn4 = *reinterpret_cast<const f16x4*>(xg + xb + (size_t)2 * HID * 64);
    }
    if (tid < NWG) {
      while (__hip_atomic_load(&flags[tid], __ATOMIC_RELAXED, __HIP_MEMORY_SCOPE_AGENT) < gen)
        __builtin_amdgcn_s_sleep(2);
    }
    __syncthreads();
    ++gen;
  }

  // persist fp32 master state for the next chunk dispatch (normal stores)
#pragma unroll
  for (int r = 0; r < 4; ++r) h32L[(size_t)(b0 + r) * HID + jj] = hold[r];
}

// ---------------- final linear: out[b] = dot(h32[b,:], Wlin) + blin ----------------
__global__ __launch_bounds__(256) void linear_kernel(
    const float* __restrict__ h32, const float* __restrict__ wlin,
    const float* __restrict__ blin, float* __restrict__ out)
{
  __shared__ float red[4];
  const int b = blockIdx.x, tid = threadIdx.x;
  float s = 0.f;
  for (int j = tid; j < HID; j += 256) s += h32[(size_t)b * HID + j] * wlin[j];
  for (int o = 32; o > 0; o >>= 1) s += __shfl_down(s, o);
  if ((tid & 63) == 0) red[tid >> 6] = s;
  __syncthreads();
  if (tid == 0) out[b] = red[0] + red[1] + red[2] + red[3] + blin[0];
}

extern "C" void kernel_launch(void* const* d_in, const int* in_sizes, int n_in,
                              void* d_out, int out_size, void* d_ws, size_t ws_size,
                              hipStream_t stream) {
  const float* x     = (const float*)d_in[0];
  const float* wih0  = (const float*)d_in[1];
  const float* wih12 = (const float*)d_in[2];
  const float* whh   = (const float*)d_in[3];
  const float* bih   = (const float*)d_in[4];
  const float* bhh   = (const float*)d_in[5];
  const float* wlin  = (const float*)d_in[6];
  const float* blin  = (const float*)d_in[7];
  float* out = (float*)d_out;

  // ---- adaptive chunking: fit workspace to ws_size (deterministic per call) ----
  const size_t fixedB = 8388608ull + 786432 + 12582912 + 18874368 + 786432 + 786432 + 1024;
  int C = 8;
  {
    const int cands[7] = {512, 256, 128, 64, 32, 16, 8};
    for (int i = 0; i < 7; ++i) {
      if (fixedB + (size_t)cands[i] * 524288ull <= ws_size) { C = cands[i]; break; }
    }
  }
  const int nch = TT / C;

  char* ws = (char*)d_ws;
  size_t o = 0;
  _Float16* XG  = (_Float16*)(ws + o); o += (size_t)C * G3 * BB * 2;    // C*384KB
  _Float16* Ych = (_Float16*)(ws + o); o += (size_t)C * BB * HID * 2;   // C*128KB
  _Float16* X16 = (_Float16*)(ws + o); o += (size_t)MROWS * 128 * 2;    // 8.39MB
  _Float16* WI0 = (_Float16*)(ws + o); o += (size_t)G3 * 128 * 2;
  _Float16* WI12= (_Float16*)(ws + o); o += (size_t)2 * G3 * HID * 2;
  _Float16* WHH = (_Float16*)(ws + o); o += (size_t)3 * G3 * HID * 2;
  _Float16* H16 = (_Float16*)(ws + o); o += (size_t)3 * 2 * BH * 2;     // per-layer dbuf
  float*    H32 = (float*)(ws + o);    o += (size_t)3 * BH * 4;         // per-layer master
  unsigned* FLG = (unsigned*)(ws + o); o += 1024;

  prep_kernel<<<dim3(2048), dim3(256), 0, stream>>>(x, wih0, wih12, whh,
                                                    X16, WI0, WI12, WHH, FLG);

  unsigned g0 = 1;
  for (int c = 0; c < nch; ++c) {
    for (int layer = 0; layer < 3; ++layer) {
      const _Float16* A  = (layer == 0) ? X16 + (size_t)c * C * 64 * 128 : Ych;
      const int K        = (layer == 0) ? 128 : HID;
      const _Float16* WI = (layer == 0) ? WI0 : WI12 + (size_t)(layer - 1) * G3 * HID;
      gemm_xg_kernel<<<dim3(24, C / 2), dim3(256), 0, stream>>>(
          A, WI, bih + layer * G3, XG, K);

      gru_scan_kernel<<<dim3(NWG), dim3(256), 0, stream>>>(
          XG, WHH + (size_t)layer * G3 * HID, bhh + layer * G3,
          (layer < 2) ? Ych : (_Float16*)nullptr,
          H32 + (size_t)layer * BH, H16 + (size_t)layer * 2 * BH,
          FLG, C, c * C, (c == 0) ? 1 : 0, g0);
      g0 += (unsigned)(C + 1);
    }
  }

  linear_kernel<<<dim3(64), dim3(256), 0, stream>>>(H32 + 2 * (size_t)BH, wlin, blin, out);
}

// Round 6
// 10947.419 us; speedup vs baseline: 1.7222x; 1.0623x over previous
//
#include <hip/hip_runtime.h>

typedef _Float16 f16x8 __attribute__((ext_vector_type(8)));
typedef float    f32x4 __attribute__((ext_vector_type(4)));

#define HID 1024
#define TT  512
#define BB  64
#define MROWS (TT*BB)   // 32768
#define G3  (3*HID)     // 3072
#define BH  (BB*HID)    // 65536

__device__ __forceinline__ f32x4 mfma16(f16x8 a, f16x8 b, f32x4 c) {
  return __builtin_amdgcn_mfma_f32_16x16x32_f16(a, b, c, 0, 0, 0);
}

__device__ __forceinline__ float sigm(float x) { return 1.f / (1.f + __expf(-x)); }
__device__ __forceinline__ float tanh_f(float x) {
  x = fminf(fmaxf(x, -20.f), 20.f);
  float e = __expf(2.f * x);
  return (e - 1.f) / (e + 1.f);
}

// ---- round-4-PROVEN device-scope primitives (sc1 = IC-coherent; relaxed agent flags) ----
#define H_LOAD16(dst, src) \
  asm volatile("global_load_dwordx4 %0, %1, off sc1" : "=v"(dst) : "v"(src))
#define H_STORE2(ptr, val16) \
  asm volatile("global_store_short %0, %1, off sc1" \
               :: "v"(ptr), "v"((unsigned)__builtin_bit_cast(unsigned short, (val16))) : "memory")
#define WAIT_VM0 \
  do { asm volatile("s_waitcnt vmcnt(0)" ::: "memory"); } while (0)

// ---------------- prep: fp32 -> fp16 casts (+ K-pad 118->128, x transpose to [t][b]) -----
__global__ __launch_bounds__(256) void prep_kernel(
    const float* __restrict__ x, const float* __restrict__ wih0,
    const float* __restrict__ wih12, const float* __restrict__ whh,
    _Float16* __restrict__ x16, _Float16* __restrict__ wi0_16,
    _Float16* __restrict__ wi12_16, _Float16* __restrict__ whh16,
    unsigned* __restrict__ flags)
{
  if (blockIdx.x == 0 && threadIdx.x < 192) flags[threadIdx.x] = 0u;  // 3 groups x 64

  const int R0 = MROWS * 128;
  const int R1 = G3 * 128;
  const int R2 = 2 * G3 * HID;
  const int R3 = 3 * G3 * HID;
  const int total = R0 + R1 + R2 + R3;
  for (int idx = blockIdx.x * 256 + threadIdx.x; idx < total; idx += gridDim.x * 256) {
    if (idx < R0) {                       // x16[t*64+b][128]
      int row = idx >> 7, k = idx & 127;
      int t = row >> 6, b = row & 63;
      x16[idx] = (k < 118) ? (_Float16)x[((size_t)b * TT + t) * 118 + k] : (_Float16)0.f;
    } else if (idx < R0 + R1) {           // W_ih0 padded [3072][128]
      int i = idx - R0;
      int row = i >> 7, k = i & 127;
      wi0_16[i] = (k < 118) ? (_Float16)wih0[(size_t)row * 118 + k] : (_Float16)0.f;
    } else if (idx < R0 + R1 + R2) {      // W_ih12 [2][3072][1024]
      int i = idx - (R0 + R1);
      wi12_16[i] = (_Float16)wih12[i];
    } else {                              // W_hh [3][3072][1024]
      int i = idx - (R0 + R1 + R2);
      whh16[i] = (_Float16)whh[i];
    }
  }
}

// one K-block of the hg MFMA: counted vmcnt (exactly 32 h-loads outstanding at entry).
// sched_barrier after the waitcnt per rule #18.
#define MFMA_KB(kb, WCNT)                                                      \
  {                                                                            \
    asm volatile("s_waitcnt vmcnt(" WCNT ")" ::: "memory");                    \
    __builtin_amdgcn_sched_barrier(0);                                         \
    _Pragma("unroll")                                                          \
    for (int kk = 0; kk < 8; ++kk) {                                           \
      const int kbyte = ((kb) * 256 + kk * 32) * 2 + kqb;                      \
      _Pragma("unroll")                                                        \
      for (int gi = 0; gi < 3; ++gi) {                                         \
        const int lr = gi * 16 + (l & 15);                                     \
        const unsigned off = (unsigned)(lr * 2048 + kbyte) ^ (unsigned)((lr & 7) << 4); \
        f16x8 bfr = *reinterpret_cast<const f16x8*>(wl_b + off);               \
        acc[gi] = mfma16(afr[kb][kk], bfr, acc[gi]);                           \
      }                                                                        \
    }                                                                          \
  }

// ---------------- fused 3-layer wavefront scan: 192 WGs = 3 groups x 64 ----------------
// Group g = layer g. WG owns 16 output cols (W_hh slice, 96KB swizzled LDS; g0 also
// W_ih0 slice, 12KB). Per step: hg MFMA from own-group h(t-1) (IC, round-4 exchange),
// gates with the xg accumulator computed ONE STEP AHEAD (during exchange slack):
//   g0: xg from x16 (K=128, LDS W_ih0); g1/g2: xg from y_{g-1}(t+1) ring (IC) with
//   W_ih12 slice streamed from L2 (constant addresses -> L2-resident).
// Layer handoff: y rings (Rv slots, pow2) + producer-group flags; backpressure via
// consumer-group flags at distance Rv. All flags: relaxed agent atomics (round-4 proven).
__global__ __launch_bounds__(256, 1) void scan_all_kernel(
    const _Float16* __restrict__ x16,   // [T*64][128]
    const _Float16* __restrict__ wi0,   // [3072][128]
    const _Float16* __restrict__ wi12,  // [2][3072][1024]
    const _Float16* __restrict__ whh,   // [3][3072][1024]
    const float* __restrict__ bih,      // [3][3072]
    const float* __restrict__ bhh,      // [3][3072]
    _Float16* y0,                       // [Rv][64][1024] ring (layer0 -> layer1)
    _Float16* y1,                       // [Rv][64][1024] ring (layer1 -> layer2)
    _Float16* h16_2,                    // [2][64][1024] parity state (layer 2)
    float* h32,                         // [64][1024] final h of layer 2
    unsigned* flt,                      // [3][64] per-group step flags (pre-zeroed)
    int rv)                             // ring slots (pow2)
{
  __shared__ __align__(16) _Float16 WL[48 * 1024];  // 96KB  W_hh slice
  __shared__ __align__(16) _Float16 WI[48 * 128];   // 12KB  W_ih0 slice (g0)
  const int g  = blockIdx.x >> 6;      // layer 0..2
  const int wg = blockIdx.x & 63;
  const int j0 = wg * 16;
  const int tid = threadIdx.x, l = tid & 63, w = tid >> 6;
  char* wl_b = reinterpret_cast<char*>(WL);
  char* wi_b = reinterpret_cast<char*>(WI);
  const int rmask = rv - 1;

  // stage W_hh slice (XOR-swizzled, G4 fix)
  {
    const _Float16* Wl = whh + (size_t)g * G3 * HID;
    for (int c = tid; c < 48 * 128; c += 256) {
      const int lr = c >> 7, kc = c & 127;
      const int gi = lr >> 4, jr = lr & 15;
      const _Float16* src = Wl + (size_t)(gi * HID + j0 + jr) * HID + kc * 8;
      unsigned byte = (unsigned)(lr * 2048 + kc * 16) ^ (unsigned)((lr & 7) << 4);
      *reinterpret_cast<uint4*>(wl_b + byte) = *reinterpret_cast<const uint4*>(src);
    }
  }
  // stage W_ih0 slice (g0 only), same swizzle at row stride 256B
  if (g == 0) {
    for (int c = tid; c < 48 * 16; c += 256) {
      const int lr = c >> 4, kc = c & 15;
      const int gi = lr >> 4, jr = lr & 15;
      const _Float16* src = wi0 + (size_t)(gi * HID + j0 + jr) * 128 + kc * 8;
      unsigned byte = (unsigned)(lr * 256 + kc * 16) ^ (unsigned)((lr & 7) << 4);
      *reinterpret_cast<uint4*>(wi_b + byte) = *reinterpret_cast<const uint4*>(src);
    }
  }
  __syncthreads();

  unsigned* fltSelf = flt + g * 64;
  unsigned* fltUp   = flt + (g - 1) * 64;   // valid for g>0
  unsigned* fltDn   = flt + (g + 1) * 64;   // valid for g<2
  _Float16* ySelf = (g == 0) ? y0 : y1;     // own output ring (g<2)
  const _Float16* yUp = (g == 1) ? y0 : y1; // consumed ring (g>0)
  const _Float16* wiL = wi12 + (size_t)(g - 1) * G3 * HID;  // g>0

  const int jj = j0 + (l & 15);             // lane's output column
  const int b0 = 16 * w + ((l >> 4) << 2);  // first of 4 batch rows (C/D map)
  const float bhr = bhh[g * G3 + jj], bhz = bhh[g * G3 + HID + jj], bhn = bhh[g * G3 + 2 * HID + jj];
  const float bir = bih[g * G3 + jj], biz = bih[g * G3 + HID + jj], bin = bih[g * G3 + 2 * HID + jj];
  const int arow = (16 * w + (l & 15)) * HID;  // A-frag row offset (row = l&15 map)
  const int kq = (l >> 4) << 3;                // A/B frag k-offset (elements)
  const int kqb = kq * 2;
  float hold[4] = {0.f, 0.f, 0.f, 0.f};

  // ---- xg accumulator for step s (computed one step ahead) ----
  f32x4 acc_x[3];
#define XG_PHASE(s)                                                                 \
  {                                                                                 \
    _Pragma("unroll")                                                               \
    for (int gi = 0; gi < 3; ++gi) acc_x[gi] = f32x4{0.f, 0.f, 0.f, 0.f};           \
    if (g == 0) {                                                                   \
      f16x8 ax[4];                                                                  \
      _Pragma("unroll")                                                             \
      for (int kk = 0; kk < 4; ++kk)                                                \
        ax[kk] = *reinterpret_cast<const f16x8*>(                                   \
            x16 + ((size_t)(s)*BB + 16 * w + (l & 15)) * 128 + kk * 32 + kq);       \
      _Pragma("unroll")                                                             \
      for (int kk = 0; kk < 4; ++kk) {                                              \
        _Pragma("unroll")                                                           \
        for (int gi = 0; gi < 3; ++gi) {                                            \
          const int lr = gi * 16 + (l & 15);                                        \
          const unsigned off =                                                      \
              (unsigned)(lr * 256 + (kk * 32 + kq) * 2) ^ (unsigned)((lr & 7) << 4);\
          f16x8 bfr = *reinterpret_cast<const f16x8*>(wi_b + off);                  \
          acc_x[gi] = mfma16(ax[kk], bfr, acc_x[gi]);                               \
        }                                                                           \
      }                                                                             \
    } else {                                                                        \
      const _Float16* ys = yUp + (size_t)((s)&rmask) * BH;                          \
      f16x8 ay[4][8];                                                               \
      _Pragma("unroll")                                                             \
      for (int kb = 0; kb < 4; ++kb)                                                \
        _Pragma("unroll")                                                           \
        for (int kk = 0; kk < 8; ++kk)                                              \
          H_LOAD16(ay[kb][kk], ys + arow + kq + kb * 256 + kk * 32);                \
      WAIT_VM0;                                                                     \
      __builtin_amdgcn_sched_barrier(0);                                            \
      for (int kb = 0; kb < 4; ++kb) {                                              \
        f16x8 bw[3][8];                                                             \
        _Pragma("unroll")                                                           \
        for (int gi = 0; gi < 3; ++gi)                                              \
          _Pragma("unroll")                                                         \
          for (int kk = 0; kk < 8; ++kk)                                            \
            bw[gi][kk] = *reinterpret_cast<const f16x8*>(                           \
                wiL + (size_t)(gi * HID + j0 + (l & 15)) * HID + kb * 256 + kk * 32 + kq); \
        _Pragma("unroll")                                                           \
        for (int kk = 0; kk < 8; ++kk)                                              \
          _Pragma("unroll")                                                         \
          for (int gi = 0; gi < 3; ++gi)                                            \
            acc_x[gi] = mfma16(ay[kb][kk], bw[gi][kk], acc_x[gi]);                  \
      }                                                                             \
      WAIT_VM0;                                                                     \
    }                                                                               \
  }

  // ---- prologue: xg(0). Consumers wait for upstream step 0 first. ----
  if (g > 0 && tid < 64) {
    while (__hip_atomic_load(&fltUp[tid], __ATOMIC_RELAXED, __HIP_MEMORY_SCOPE_AGENT) < 1u)
      __builtin_amdgcn_s_sleep(1);
  }
  __syncthreads();
  XG_PHASE(0)

  for (int t = 0; t < TT; ++t) {
    // arrival: own-group h(t-1) visible; backpressure for ring slot reuse
    if (tid < 64) {
      if (t >= 1) {
        while (__hip_atomic_load(&fltSelf[tid], __ATOMIC_RELAXED, __HIP_MEMORY_SCOPE_AGENT) < (unsigned)t)
          __builtin_amdgcn_s_sleep(1);
      }
      if (g < 2 && t >= rv) {
        while (__hip_atomic_load(&fltDn[tid], __ATOMIC_RELAXED, __HIP_MEMORY_SCOPE_AGENT) < (unsigned)(t - rv + 1))
          __builtin_amdgcn_s_sleep(1);
      }
    }
    __syncthreads();

    f32x4 acc[3];
#pragma unroll
    for (int gi = 0; gi < 3; ++gi) acc[gi] = f32x4{0.f, 0.f, 0.f, 0.f};

    if (t >= 1) {   // hg = h(t-1) @ W_hh^T
      const _Float16* hsrc = (g == 2) ? h16_2 + (size_t)(t & 1) * BH
                                      : ySelf + (size_t)((t - 1) & rmask) * BH;
      f16x8 afr[4][8];
#pragma unroll
      for (int kb = 0; kb < 4; ++kb)
#pragma unroll
        for (int kk = 0; kk < 8; ++kk)
          H_LOAD16(afr[kb][kk], hsrc + arow + kq + kb * 256 + kk * 32);
      MFMA_KB(0, "24")
      MFMA_KB(1, "16")
      MFMA_KB(2, "8")
      MFMA_KB(3, "0")
    }

    _Float16 hout[4];
#pragma unroll
    for (int r = 0; r < 4; ++r) {
      const float rg = sigm(acc_x[0][r] + bir + acc[0][r] + bhr);
      const float zg = sigm(acc_x[1][r] + biz + acc[1][r] + bhz);
      const float ng = tanh_f(acc_x[2][r] + bin + rg * (acc[2][r] + bhn));
      const float hv = (1.f - zg) * ng + zg * hold[r];
      hold[r] = hv;
      hout[r] = (_Float16)hv;
    }
    if (g == 2) {
#pragma unroll
      for (int r = 0; r < 4; ++r)
        H_STORE2(h16_2 + (size_t)((t & 1) ^ 1) * BH + (size_t)(b0 + r) * HID + jj, hout[r]);
      if (t == TT - 1) {
#pragma unroll
        for (int r = 0; r < 4; ++r) h32[(size_t)(b0 + r) * HID + jj] = hold[r];
      }
    } else {
#pragma unroll
      for (int r = 0; r < 4; ++r)
        H_STORE2(ySelf + (size_t)(t & rmask) * BH + (size_t)(b0 + r) * HID + jj, hout[r]);
    }

    WAIT_VM0;                       // own sc1 stores acked at IC
    __syncthreads();
    if (tid == 0)
      __hip_atomic_store(&fltSelf[wg], (unsigned)(t + 1), __ATOMIC_RELAXED, __HIP_MEMORY_SCOPE_AGENT);

    // xg(t+1) during the exchange slack
    if (t + 1 < TT) {
      if (g > 0 && tid < 64) {
        while (__hip_atomic_load(&fltUp[tid], __ATOMIC_RELAXED, __HIP_MEMORY_SCOPE_AGENT) < (unsigned)(t + 2))
          __builtin_amdgcn_s_sleep(1);
      }
      __syncthreads();
      XG_PHASE(t + 1)
    }
  }
}

// ---------------- final linear: out[b] = dot(h32[b,:], Wlin) + blin ----------------
__global__ __launch_bounds__(256) void linear_kernel(
    const float* __restrict__ h32, const float* __restrict__ wlin,
    const float* __restrict__ blin, float* __restrict__ out)
{
  __shared__ float red[4];
  const int b = blockIdx.x, tid = threadIdx.x;
  float s = 0.f;
  for (int j = tid; j < HID; j += 256) s += h32[(size_t)b * HID + j] * wlin[j];
  for (int o = 32; o > 0; o >>= 1) s += __shfl_down(s, o);
  if ((tid & 63) == 0) red[tid >> 6] = s;
  __syncthreads();
  if (tid == 0) out[b] = red[0] + red[1] + red[2] + red[3] + blin[0];
}

extern "C" void kernel_launch(void* const* d_in, const int* in_sizes, int n_in,
                              void* d_out, int out_size, void* d_ws, size_t ws_size,
                              hipStream_t stream) {
  const float* x     = (const float*)d_in[0];
  const float* wih0  = (const float*)d_in[1];
  const float* wih12 = (const float*)d_in[2];
  const float* whh   = (const float*)d_in[3];
  const float* bih   = (const float*)d_in[4];
  const float* bhh   = (const float*)d_in[5];
  const float* wlin  = (const float*)d_in[6];
  const float* blin  = (const float*)d_in[7];
  float* out = (float*)d_out;

  // fixed ~41.2MB; rings 2 x Rv x 128KB. Pick largest pow2 Rv that fits.
  const size_t fixedB = 8388608ull + 786432 + 12582912 + 18874368 + 262144 + 262144 + 1024;
  int rv = 32;
  {
    const int cands[4] = {256, 128, 64, 32};
    for (int i = 0; i < 4; ++i) {
      if (fixedB + 2ull * (size_t)cands[i] * 131072ull <= ws_size) { rv = cands[i]; break; }
    }
  }

  char* ws = (char*)d_ws;
  size_t o = 0;
  _Float16* X16 = (_Float16*)(ws + o); o += (size_t)MROWS * 128 * 2;     // 8.39MB
  _Float16* WI0 = (_Float16*)(ws + o); o += (size_t)G3 * 128 * 2;        // 0.79MB
  _Float16* WI12= (_Float16*)(ws + o); o += (size_t)2 * G3 * HID * 2;    // 12.58MB
  _Float16* WHH = (_Float16*)(ws + o); o += (size_t)3 * G3 * HID * 2;    // 18.87MB
  _Float16* H162= (_Float16*)(ws + o); o += (size_t)2 * BH * 2;          // 0.26MB
  float*    H32 = (float*)(ws + o);    o += (size_t)BH * 4;              // 0.26MB
  unsigned* FLT = (unsigned*)(ws + o); o += 1024;                        // 3 x 64 flags
  _Float16* Y0  = (_Float16*)(ws + o); o += (size_t)rv * BH * 2;         // ring
  _Float16* Y1  = (_Float16*)(ws + o); o += (size_t)rv * BH * 2;         // ring

  prep_kernel<<<dim3(2048), dim3(256), 0, stream>>>(x, wih0, wih12, whh,
                                                    X16, WI0, WI12, WHH, FLT);

  scan_all_kernel<<<dim3(192), dim3(256), 0, stream>>>(
      X16, WI0, WI12, WHH, bih, bhh, Y0, Y1, H162, H32, FLT, rv);

  linear_kernel<<<dim3(64), dim3(256), 0, stream>>>(H32, wlin, blin, out);
}